// Round 15
// baseline (63.252 us; speedup 1.0000x reference)
//
#include <hip/hip_runtime.h>
#include <cstdint>
#include <cstddef>
#include <utility>

#define HH 256
#define WW 256
#define CIN 16
#define COUT 32
#define NB 2
#define TW 32
#define TH 8
#define NPIX (TW*TH)            // 256 pixels/block
#define HALO 5
#define LR_ROWS (TH + 2*HALO)   // 18
#define LR_COLS (TW + 2*HALO)   // 42
#define NCELL (LR_ROWS*LR_COLS) // 756
#define HW (HH*WW)

typedef float f32x2 __attribute__((ext_vector_type(2)));
typedef float f32x4 __attribute__((ext_vector_type(4)));
typedef float f32x8 __attribute__((ext_vector_type(8)));
typedef int   i32x4 __attribute__((ext_vector_type(4)));
typedef short bf16x8 __attribute__((ext_vector_type(8)));
__device__ __forceinline__ f32x2 splat2(float v) { return f32x2{v, v}; }

// RNE f32->bf16 (bit trick == HW cvt for finite values) — used in pack_A only
__device__ __forceinline__ unsigned short f2bf(float f) {
  unsigned u = __float_as_uint(f);
  return (unsigned short)((u + 0x7fffu + ((u >> 16) & 1u)) >> 16);
}

// ---------------- compile-time offset tables ----------------
struct alignas(16) Tables {
  int16_t coff[256];    // (g*16+n) -> cell offset dx*LR_COLS+dy (phase 2)
  int16_t pcoff[128];   // dedup'd distinct-pair cell offsets
  uint8_t gmap[256];    // (g*16+n) -> dedup index (phase-1 tree wiring)
  int np;
};

// numpy round-half-to-even for non-negative v (only .0/.5 cases occur)
constexpr int rhe(double v) {
  int f = (int)v;
  double fr = v - (double)f;
  if (fr > 0.5) return f + 1;
  if (fr < 0.5) return f;
  return (f & 1) ? f + 1 : f;
}

constexpr Tables make_tables() {
  Tables t{};
  t.np = 0;
  for (int g = 0; g < 16; ++g) {
    int hp = (g >> 2) + 2;   // rb + gh
    int wp = (g & 3) + 2;    // rb + gw
    int TD[5] = {}, LRr[3] = {};
    for (int j = 0; j < 5; ++j) TD[j] = rhe(j * wp / 2.0) - wp;
    for (int j = 0; j < 3; ++j) LRr[j] = rhe((j + 1) * hp / 2.0) - hp;
    int dxs[16] = {}, dys[16] = {};
    for (int j = 0; j < 5; ++j) { dxs[j]      = -hp;    dys[j]      = TD[j]; }
    for (int j = 0; j < 3; ++j) { dxs[5 + j]  = LRr[j]; dys[5 + j]  =  wp;   }
    for (int j = 0; j < 5; ++j) { dxs[8 + j]  =  hp;    dys[8 + j]  = TD[j]; }
    for (int j = 0; j < 3; ++j) { dxs[13 + j] = LRr[j]; dys[13 + j] = -wp;   }
    for (int n = 0; n < 16; ++n) {
      int co = dxs[n] * LR_COLS + dys[n];
      t.coff[g * 16 + n] = (int16_t)co;
      int d = -1;
      for (int k = 0; k < t.np; ++k)
        if ((int)t.pcoff[k] == co) { d = k; break; }
      if (d < 0) { d = t.np; t.np++; t.pcoff[d] = (int16_t)co; }
      t.gmap[g * 16 + n] = (uint8_t)d;
    }
  }
  return t;
}

constexpr Tables CT = make_tables();
constexpr int NP = CT.np;
static_assert(NP <= 128, "pair table overflow");
static_assert(NP % 8 == 0, "oct remainder");
__device__ const Tables DT = make_tables();   // for runtime-indexed phase-2 reads

// ------- exact transcription of numpy's SIMD f32 exp, 2-wide packed -------
__device__ __forceinline__ f32x2 numpy_expf2(f32x2 v) {
#pragma clang fp contract(off)
  const f32x2 MAGIC = splat2(12582912.0f);         // 1.5 * 2^23
  f32x2 q = __builtin_elementwise_fma(v, splat2(1.442695040888963407359e+00f), MAGIC);
  q = q - MAGIC;                                   // rint(v*log2e), single rounding
  f32x2 r = __builtin_elementwise_fma(q, splat2(-6.93145752e-1f), v);
  r = __builtin_elementwise_fma(q, splat2(-1.42860677e-6f), r);
  f32x2 num = __builtin_elementwise_fma(splat2(5.082762527590693718096e-04f), r,
                                        splat2(6.757896990527504603057e-03f));
  num = __builtin_elementwise_fma(num, r, splat2(5.114512081637298353406e-02f));
  num = __builtin_elementwise_fma(num, r, splat2(2.473615434895520810817e-01f));
  num = __builtin_elementwise_fma(num, r, splat2(7.257664613233124478488e-01f));
  num = __builtin_elementwise_fma(num, r, splat2(9.999999999980870924916e-01f));
  f32x2 den = __builtin_elementwise_fma(splat2(2.159509375685829852307e-02f), r,
                                        splat2(-2.742335390411667452936e-01f));
  den = __builtin_elementwise_fma(den, r, splat2(1.0f));
  f32x2 res;
  res.x = ldexpf(num.x / den.x, (int)q.x);         // IEEE div + exact pow2 scale
  res.y = ldexpf(num.y / den.y, (int)q.y);
  return res;
}

// ---- shared pair-OCT body: ONE copy of code, 8 independent chains for ILP ----
__device__ __attribute__((noinline))
f32x8 pair8(const float4* __restrict__ xt4,
            int c0, int c1, int c2, int c3, int c4, int c5, int c6, int c7,
            float4 xc0, float4 xc1, float4 xc2, float4 xc3)
{
#pragma clang fp contract(off)
  const f32x2 xcl[8] = { {xc0.x,xc0.y},{xc0.z,xc0.w},{xc1.x,xc1.y},{xc1.z,xc1.w},
                         {xc2.x,xc2.y},{xc2.z,xc2.w},{xc3.x,xc3.y},{xc3.z,xc3.w} };
  const int cells[8] = {c0, c1, c2, c3, c4, c5, c6, c7};
  float mloc[8];
#pragma unroll
  for (int j = 0; j < 8; ++j) {
    const int cell = cells[j];
    float4 R0 = xt4[0 * NCELL + cell];
    float4 R1 = xt4[1 * NCELL + cell];
    float4 R2 = xt4[2 * NCELL + cell];
    float4 R3 = xt4[3 * NCELL + cell];
    // products rounded individually (v_pk_mul pairs 2 IEEE muls/slot)
    f32x2 pr[8];
    pr[0] = f32x2{R0.x, R0.y} * xcl[0];  pr[1] = f32x2{R0.z, R0.w} * xcl[1];
    pr[2] = f32x2{R1.x, R1.y} * xcl[2];  pr[3] = f32x2{R1.z, R1.w} * xcl[3];
    pr[4] = f32x2{R2.x, R2.y} * xcl[4];  pr[5] = f32x2{R2.z, R2.w} * xcl[5];
    pr[6] = f32x2{R3.x, R3.y} * xcl[6];  pr[7] = f32x2{R3.z, R3.w} * xcl[7];
    // sequential channel sum c=0..15 (numpy outer-axis reduce), unfused
    float s = pr[0].x;
    s += pr[0].y; s += pr[1].x; s += pr[1].y;
    s += pr[2].x; s += pr[2].y; s += pr[3].x; s += pr[3].y;
    s += pr[4].x; s += pr[4].y; s += pr[5].x; s += pr[5].y;
    s += pr[6].x; s += pr[6].y; s += pr[7].x; s += pr[7].y;
    mloc[j] = s / 16.0f;                     // exact (pow2)
  }
  f32x8 outv;
#pragma unroll
  for (int h = 0; h < 4; ++h) {
    f32x2 e = numpy_expf2(-f32x2{mloc[2*h], mloc[2*h+1]});
    f32x2 d = splat2(1.0f) + e;
    outv[2*h]     = 1.0f / d.x;              // IEEE f32 div
    outv[2*h + 1] = 1.0f / d.y;
  }
  return outv;
}

template<size_t... BB>
__device__ __forceinline__ void pairs_call(float* sgv, std::index_sequence<BB...>,
    const float4* xt4, int lbase, float4 xc0, float4 xc1, float4 xc2, float4 xc3)
{
  ((void)([&] {
    f32x8 r = pair8(xt4,
                    lbase + (int)CT.pcoff[BB*8 + 0], lbase + (int)CT.pcoff[BB*8 + 1],
                    lbase + (int)CT.pcoff[BB*8 + 2], lbase + (int)CT.pcoff[BB*8 + 3],
                    lbase + (int)CT.pcoff[BB*8 + 4], lbase + (int)CT.pcoff[BB*8 + 5],
                    lbase + (int)CT.pcoff[BB*8 + 6], lbase + (int)CT.pcoff[BB*8 + 7],
                    xc0, xc1, xc2, xc3);
    sgv[BB*8 + 0] = r[0]; sgv[BB*8 + 1] = r[1];    // static indices -> registers
    sgv[BB*8 + 2] = r[2]; sgv[BB*8 + 3] = r[3];
    sgv[BB*8 + 4] = r[4]; sgv[BB*8 + 5] = r[5];
    sgv[BB*8 + 6] = r[6]; sgv[BB*8 + 7] = r[7];
  }()), ...);
}

// -------- A-operand pack: w[o][c][n] -> per-lane MFMA fragment order --------
__global__ void pack_A(const float* __restrict__ w, unsigned short* __restrict__ wsA) {
  int i = blockIdx.x * 256 + threadIdx.x;
  if (i < 2 * 8 * 64 * 8) {
    int m = i >> 12, s = (i >> 9) & 7, l = (i >> 3) & 63, j = i & 7;
    int h = l >> 4, col = l & 15;
    int o = m * 16 + col;
    int n = 2 * s + (h >> 1);
    int c = (h & 1) * 8 + j;
    wsA[i] = f2bf(w[(o * CIN + c) * 16 + n]);
  }
}

// ---------------- fused main kernel ----------------
__global__ __launch_bounds__(TW * TH)
__attribute__((amdgpu_waves_per_eu(2, 2)))
void adapkc_main(
    const float* __restrict__ x, const unsigned short* __restrict__ wsA,
    const float* __restrict__ bias, float* __restrict__ out)
{
#pragma clang fp contract(off)   // numpy never fuses mul+add; keep every rounding
  __shared__ float4 xt4[4 * NCELL];          // 48,384 B
  __shared__ int    ori_s[NPIX];             //  1,024 B

  const int tx = threadIdx.x, ty = threadIdx.y;
  const int tid = ty * TW + tx;
  const int b = blockIdx.z;
  const int h0 = blockIdx.y * TH, w0 = blockIdx.x * TW;

  // ---- stage x tile (+halo 5, zero-padded) ----
  for (int i = tid; i < NCELL; i += TW * TH) {
    int r = i / LR_COLS, cc = i - r * LR_COLS;
    int gh = h0 - HALO + r, gw = w0 - HALO + cc;
    bool ok = (gh >= 0) & (gh < HH) & (gw >= 0) & (gw < WW);
    const float* xp = x + (size_t)b * (CIN * HW) + gh * WW + gw;
#pragma unroll
    for (int q = 0; q < 4; ++q) {
      float4 v = make_float4(0.f, 0.f, 0.f, 0.f);
      if (ok) {
        v.x = xp[(q * 4 + 0) * HW];
        v.y = xp[(q * 4 + 1) * HW];
        v.z = xp[(q * 4 + 2) * HW];
        v.w = xp[(q * 4 + 3) * HW];
      }
      xt4[q * NCELL + i] = v;
    }
  }
  __syncthreads();

  const int lbase = (ty + HALO) * LR_COLS + (tx + HALO);
  const float4 xc0 = xt4[0 * NCELL + lbase];
  const float4 xc1 = xt4[1 * NCELL + lbase];
  const float4 xc2 = xt4[2 * NCELL + lbase];
  const float4 xc3 = xt4[3 * NCELL + lbase];

  // ---- phase 1a: 14 calls into ONE pair-oct body (8-way ILP) ----
  float sgv[NP];
  pairs_call(sgv, std::make_index_sequence<NP / 8>{}, xt4, lbase, xc0, xc1, xc2, xc3);

  // ---- phase 1b: per-group numpy SSE2 pairwise tree (compile-time wiring) ----
  float sim32[16];
#pragma unroll
  for (int g = 0; g < 16; ++g) {
    float A0 = (sgv[CT.gmap[g*16+0]]  + sgv[CT.gmap[g*16+8]])
             + (sgv[CT.gmap[g*16+4]]  + sgv[CT.gmap[g*16+12]]);
    float A1 = (sgv[CT.gmap[g*16+1]]  + sgv[CT.gmap[g*16+9]])
             + (sgv[CT.gmap[g*16+5]]  + sgv[CT.gmap[g*16+13]]);
    float A2 = (sgv[CT.gmap[g*16+2]]  + sgv[CT.gmap[g*16+10]])
             + (sgv[CT.gmap[g*16+6]]  + sgv[CT.gmap[g*16+14]]);
    float A3 = (sgv[CT.gmap[g*16+3]]  + sgv[CT.gmap[g*16+11]])
             + (sgv[CT.gmap[g*16+7]]  + sgv[CT.gmap[g*16+15]]);
    float ssum = (A0 + A2) + (A1 + A3);
    sim32[g] = ssum / 16.0f;                 // exact (pow2)
  }

  // ---- selection: rolled bubble (bit-exact vs triangular version) ----
  float s16[16]; int od[16];
#pragma unroll
  for (int i = 0; i < 16; ++i) { s16[i] = sim32[i]; od[i] = i; }
#pragma clang loop unroll(disable)
  for (int p = 0; p < 15; ++p) {
#pragma unroll
    for (int j = 0; j < 15; ++j) {
      float a = s16[j], c = s16[j + 1];
      int oa = od[j], oc = od[j + 1];
      bool sw = a > c;                     // strict -> stable
      s16[j] = sw ? c : a; s16[j + 1] = sw ? a : c;
      od[j] = sw ? oc : oa; od[j + 1] = sw ? oa : oc;
    }
  }
  float best = s16[1] - s16[0]; int ori = od[0];
#pragma unroll
  for (int i = 1; i < 15; ++i) {
    float dd = s16[i + 1] - s16[i];
    if (dd > best) { best = dd; ori = od[i]; }   // strict -> first max
  }
  if (!(best >= 0.001f)) ori = 0;                // INIT_INDEX

  ori_s[tid] = ori;
  __syncthreads();

  // ---- phase 2: bf16 MFMA.  D[o][pix] = sum_k W[o,k] P[k,pix], K=256 ----
  const int lane  = tid & 63;
  const int wavei = tid >> 6;
  const int hq  = lane >> 4;         // quarter-group
  const int col = lane & 15;         // D column = pixel-within-group
  const int q0  = (hq & 1) * 2;      // this lane's channel-half chunks

  bf16x8 afr[2][8];
#pragma unroll
  for (int m = 0; m < 2; ++m)
#pragma unroll
    for (int s = 0; s < 8; ++s)
      afr[m][s] = *(const bf16x8*)(wsA + (((m * 8 + s) * 64 + lane) << 3));

  float bv[2][4];
#pragma unroll
  for (int m = 0; m < 2; ++m)
#pragma unroll
    for (int r = 0; r < 4; ++r) bv[m][r] = bias[m * 16 + hq * 4 + r];

  f32x4 acc[2][4];
#pragma unroll
  for (int m = 0; m < 2; ++m)
#pragma unroll
    for (int t = 0; t < 4; ++t)
      acc[m][t] = f32x4{bv[m][0], bv[m][1], bv[m][2], bv[m][3]};

#pragma unroll
  for (int t = 0; t < 4; ++t) {
    const int p  = wavei * 64 + t * 16 + col;   // pixel this lane serves
    const int py = p >> 5, px = p & 31;
    const int lb = (py + HALO) * LR_COLS + (px + HALO);
    const int orip = ori_s[p];
    const int4* cr = (const int4*)&DT.coff[orip * 16];
    int4 cA = cr[0], cB = cr[1];
    int dw[8] = {cA.x, cA.y, cA.z, cA.w, cB.x, cB.y, cB.z, cB.w};
    const float4 xca = xt4[q0 * NCELL + lb];
    const float4 xcb = xt4[(q0 + 1) * NCELL + lb];
#pragma unroll
    for (int s = 0; s < 8; ++s) {
      int pk = dw[s];
      int off16 = (hq >= 2) ? (int)(int16_t)((unsigned)pk >> 16)
                            : (int)(int16_t)(pk & 0xffff);
      int cell = lb + off16;
      float4 ra = xt4[q0 * NCELL + cell];
      float4 rb = xt4[(q0 + 1) * NCELL + cell];
      // x_prf = xc - xr via pk_sub, then HW pack-convert pairs to bf16 (RNE)
      f32x2 d0 = f32x2{xca.x, xca.y} - f32x2{ra.x, ra.y};
      f32x2 d1 = f32x2{xca.z, xca.w} - f32x2{ra.z, ra.w};
      f32x2 d2 = f32x2{xcb.x, xcb.y} - f32x2{rb.x, rb.y};
      f32x2 d3 = f32x2{xcb.z, xcb.w} - f32x2{rb.z, rb.w};
      i32x4 wv;
      asm("v_cvt_pk_bf16_f32 %0, %1, %2" : "=v"(wv.x) : "v"(d0.x), "v"(d0.y));
      asm("v_cvt_pk_bf16_f32 %0, %1, %2" : "=v"(wv.y) : "v"(d1.x), "v"(d1.y));
      asm("v_cvt_pk_bf16_f32 %0, %1, %2" : "=v"(wv.z) : "v"(d2.x), "v"(d2.y));
      asm("v_cvt_pk_bf16_f32 %0, %1, %2" : "=v"(wv.w) : "v"(d3.x), "v"(d3.y));
      bf16x8 bfr = __builtin_bit_cast(bf16x8, wv);
      acc[0][t] = __builtin_amdgcn_mfma_f32_16x16x32_bf16(afr[0][s], bfr, acc[0][t], 0, 0, 0);
      acc[1][t] = __builtin_amdgcn_mfma_f32_16x16x32_bf16(afr[1][s], bfr, acc[1][t], 0, 0, 0);
    }
  }

  // ---- store: D row = o = m*16 + hq*4 + r; D col = pixel p(t, col) ----
#pragma unroll
  for (int t = 0; t < 4; ++t) {
    const int p  = wavei * 64 + t * 16 + col;
    const int hh = h0 + (p >> 5), ww = w0 + (p & 31);
    float* op = out + (size_t)b * (COUT * HW) + hh * WW + ww;
#pragma unroll
    for (int m = 0; m < 2; ++m)
#pragma unroll
      for (int r = 0; r < 4; ++r)
        op[(m * 16 + hq * 4 + r) * HW] = acc[m][t][r];
  }
}

extern "C" void kernel_launch(void* const* d_in, const int* in_sizes, int n_in,
                              void* d_out, int out_size, void* d_ws, size_t ws_size,
                              hipStream_t stream) {
  const float* x    = (const float*)d_in[0];
  const float* w    = (const float*)d_in[1];
  const float* bias = (const float*)d_in[2];
  float* out = (float*)d_out;
  unsigned short* wsA = (unsigned short*)d_ws;   // 8192 bf16 = 16 KB scratch

  hipLaunchKernelGGL(pack_A, dim3(32), dim3(256), 0, stream, w, wsA);

  dim3 grid(WW / TW, HH / TH, NB);
  dim3 block(TW, TH, 1);
  hipLaunchKernelGGL(adapkc_main, grid, block, 0, stream, x, wsA, bias, out);
}

// Round 16
// 63.213 us; speedup vs baseline: 1.0006x; 1.0006x over previous
//
#include <hip/hip_runtime.h>
#include <cstdint>
#include <cstddef>
#include <utility>

#define HH 256
#define WW 256
#define CIN 16
#define COUT 32
#define NB 2
#define TW 32
#define TH 8
#define NPIX (TW*TH)            // 256 pixels/block
#define HALO 5
#define LR_ROWS (TH + 2*HALO)   // 18
#define LR_COLS (TW + 2*HALO)   // 42
#define NCELL (LR_ROWS*LR_COLS) // 756 cells staged
#define NCELLP 758              // plane stride: 758 mod 8 = 6 -> plane bank-phases {0,6,4,2}
#define HW (HH*WW)

typedef float f32x2 __attribute__((ext_vector_type(2)));
typedef float f32x4 __attribute__((ext_vector_type(4)));
typedef float f32x8 __attribute__((ext_vector_type(8)));
typedef int   i32x4 __attribute__((ext_vector_type(4)));
typedef short bf16x8 __attribute__((ext_vector_type(8)));
__device__ __forceinline__ f32x2 splat2(float v) { return f32x2{v, v}; }

// RNE f32->bf16 (bit trick == HW cvt for finite values) — used in pack_A only
__device__ __forceinline__ unsigned short f2bf(float f) {
  unsigned u = __float_as_uint(f);
  return (unsigned short)((u + 0x7fffu + ((u >> 16) & 1u)) >> 16);
}

// ---------------- compile-time offset tables ----------------
struct alignas(16) Tables {
  int16_t coff[256];    // (g*16+n) -> cell offset dx*LR_COLS+dy (phase 2)
  int16_t pcoff[128];   // dedup'd distinct-pair cell offsets
  uint8_t gmap[256];    // (g*16+n) -> dedup index (phase-1 tree wiring)
  int np;
};

// numpy round-half-to-even for non-negative v (only .0/.5 cases occur)
constexpr int rhe(double v) {
  int f = (int)v;
  double fr = v - (double)f;
  if (fr > 0.5) return f + 1;
  if (fr < 0.5) return f;
  return (f & 1) ? f + 1 : f;
}

constexpr Tables make_tables() {
  Tables t{};
  t.np = 0;
  for (int g = 0; g < 16; ++g) {
    int hp = (g >> 2) + 2;   // rb + gh
    int wp = (g & 3) + 2;    // rb + gw
    int TD[5] = {}, LRr[3] = {};
    for (int j = 0; j < 5; ++j) TD[j] = rhe(j * wp / 2.0) - wp;
    for (int j = 0; j < 3; ++j) LRr[j] = rhe((j + 1) * hp / 2.0) - hp;
    int dxs[16] = {}, dys[16] = {};
    for (int j = 0; j < 5; ++j) { dxs[j]      = -hp;    dys[j]      = TD[j]; }
    for (int j = 0; j < 3; ++j) { dxs[5 + j]  = LRr[j]; dys[5 + j]  =  wp;   }
    for (int j = 0; j < 5; ++j) { dxs[8 + j]  =  hp;    dys[8 + j]  = TD[j]; }
    for (int j = 0; j < 3; ++j) { dxs[13 + j] = LRr[j]; dys[13 + j] = -wp;   }
    for (int n = 0; n < 16; ++n) {
      int co = dxs[n] * LR_COLS + dys[n];
      t.coff[g * 16 + n] = (int16_t)co;
      int d = -1;
      for (int k = 0; k < t.np; ++k)
        if ((int)t.pcoff[k] == co) { d = k; break; }
      if (d < 0) { d = t.np; t.np++; t.pcoff[d] = (int16_t)co; }
      t.gmap[g * 16 + n] = (uint8_t)d;
    }
  }
  return t;
}

constexpr Tables CT = make_tables();
constexpr int NP = CT.np;
static_assert(NP <= 128, "pair table overflow");
static_assert(NP % 8 == 0, "oct remainder");
__device__ const Tables DT = make_tables();   // for runtime-indexed phase-2 reads

// ------- exact transcription of numpy's SIMD f32 exp, 2-wide packed -------
__device__ __forceinline__ f32x2 numpy_expf2(f32x2 v) {
#pragma clang fp contract(off)
  const f32x2 MAGIC = splat2(12582912.0f);         // 1.5 * 2^23
  f32x2 q = __builtin_elementwise_fma(v, splat2(1.442695040888963407359e+00f), MAGIC);
  q = q - MAGIC;                                   // rint(v*log2e), single rounding
  f32x2 r = __builtin_elementwise_fma(q, splat2(-6.93145752e-1f), v);
  r = __builtin_elementwise_fma(q, splat2(-1.42860677e-6f), r);
  f32x2 num = __builtin_elementwise_fma(splat2(5.082762527590693718096e-04f), r,
                                        splat2(6.757896990527504603057e-03f));
  num = __builtin_elementwise_fma(num, r, splat2(5.114512081637298353406e-02f));
  num = __builtin_elementwise_fma(num, r, splat2(2.473615434895520810817e-01f));
  num = __builtin_elementwise_fma(num, r, splat2(7.257664613233124478488e-01f));
  num = __builtin_elementwise_fma(num, r, splat2(9.999999999980870924916e-01f));
  f32x2 den = __builtin_elementwise_fma(splat2(2.159509375685829852307e-02f), r,
                                        splat2(-2.742335390411667452936e-01f));
  den = __builtin_elementwise_fma(den, r, splat2(1.0f));
  f32x2 res;
  res.x = ldexpf(num.x / den.x, (int)q.x);         // IEEE div + exact pow2 scale
  res.y = ldexpf(num.y / den.y, (int)q.y);
  return res;
}

// ---- shared pair-OCT body: ONE copy of code, 8 independent chains for ILP ----
__device__ __attribute__((noinline))
f32x8 pair8(const float4* __restrict__ xt4,
            int c0, int c1, int c2, int c3, int c4, int c5, int c6, int c7,
            float4 xc0, float4 xc1, float4 xc2, float4 xc3)
{
#pragma clang fp contract(off)
  const f32x2 xcl[8] = { {xc0.x,xc0.y},{xc0.z,xc0.w},{xc1.x,xc1.y},{xc1.z,xc1.w},
                         {xc2.x,xc2.y},{xc2.z,xc2.w},{xc3.x,xc3.y},{xc3.z,xc3.w} };
  const int cells[8] = {c0, c1, c2, c3, c4, c5, c6, c7};
  float mloc[8];
#pragma unroll
  for (int j = 0; j < 8; ++j) {
    const int cell = cells[j];
    float4 R0 = xt4[0 * NCELLP + cell];
    float4 R1 = xt4[1 * NCELLP + cell];
    float4 R2 = xt4[2 * NCELLP + cell];
    float4 R3 = xt4[3 * NCELLP + cell];
    // products rounded individually (v_pk_mul pairs 2 IEEE muls/slot)
    f32x2 pr[8];
    pr[0] = f32x2{R0.x, R0.y} * xcl[0];  pr[1] = f32x2{R0.z, R0.w} * xcl[1];
    pr[2] = f32x2{R1.x, R1.y} * xcl[2];  pr[3] = f32x2{R1.z, R1.w} * xcl[3];
    pr[4] = f32x2{R2.x, R2.y} * xcl[4];  pr[5] = f32x2{R2.z, R2.w} * xcl[5];
    pr[6] = f32x2{R3.x, R3.y} * xcl[6];  pr[7] = f32x2{R3.z, R3.w} * xcl[7];
    // sequential channel sum c=0..15 (numpy outer-axis reduce), unfused
    float s = pr[0].x;
    s += pr[0].y; s += pr[1].x; s += pr[1].y;
    s += pr[2].x; s += pr[2].y; s += pr[3].x; s += pr[3].y;
    s += pr[4].x; s += pr[4].y; s += pr[5].x; s += pr[5].y;
    s += pr[6].x; s += pr[6].y; s += pr[7].x; s += pr[7].y;
    mloc[j] = s / 16.0f;                     // exact (pow2)
  }
  f32x8 outv;
#pragma unroll
  for (int h = 0; h < 4; ++h) {
    f32x2 e = numpy_expf2(-f32x2{mloc[2*h], mloc[2*h+1]});
    f32x2 d = splat2(1.0f) + e;
    outv[2*h]     = 1.0f / d.x;              // IEEE f32 div
    outv[2*h + 1] = 1.0f / d.y;
  }
  return outv;
}

template<size_t... BB>
__device__ __forceinline__ void pairs_call(float* sgv, std::index_sequence<BB...>,
    const float4* xt4, int lbase, float4 xc0, float4 xc1, float4 xc2, float4 xc3)
{
  ((void)([&] {
    f32x8 r = pair8(xt4,
                    lbase + (int)CT.pcoff[BB*8 + 0], lbase + (int)CT.pcoff[BB*8 + 1],
                    lbase + (int)CT.pcoff[BB*8 + 2], lbase + (int)CT.pcoff[BB*8 + 3],
                    lbase + (int)CT.pcoff[BB*8 + 4], lbase + (int)CT.pcoff[BB*8 + 5],
                    lbase + (int)CT.pcoff[BB*8 + 6], lbase + (int)CT.pcoff[BB*8 + 7],
                    xc0, xc1, xc2, xc3);
    sgv[BB*8 + 0] = r[0]; sgv[BB*8 + 1] = r[1];    // static indices -> registers
    sgv[BB*8 + 2] = r[2]; sgv[BB*8 + 3] = r[3];
    sgv[BB*8 + 4] = r[4]; sgv[BB*8 + 5] = r[5];
    sgv[BB*8 + 6] = r[6]; sgv[BB*8 + 7] = r[7];
  }()), ...);
}

// -------- A-operand pack: w[o][c][n] -> per-lane MFMA fragment order --------
__global__ void pack_A(const float* __restrict__ w, unsigned short* __restrict__ wsA) {
  int i = blockIdx.x * 256 + threadIdx.x;
  if (i < 2 * 8 * 64 * 8) {
    int m = i >> 12, s = (i >> 9) & 7, l = (i >> 3) & 63, j = i & 7;
    int h = l >> 4, col = l & 15;
    int o = m * 16 + col;
    int n = 2 * s + (h >> 1);
    int c = (h & 1) * 8 + j;
    wsA[i] = f2bf(w[(o * CIN + c) * 16 + n]);
  }
}

// ---------------- fused main kernel ----------------
__global__ __launch_bounds__(TW * TH)
__attribute__((amdgpu_waves_per_eu(2, 2)))
void adapkc_main(
    const float* __restrict__ x, const unsigned short* __restrict__ wsA,
    const float* __restrict__ bias, float* __restrict__ out)
{
#pragma clang fp contract(off)   // numpy never fuses mul+add; keep every rounding
  __shared__ float4 xt4[4 * NCELLP];         // 48,512 B (padded plane stride)
  __shared__ int    ori_s[NPIX];             //  1,024 B

  const int tx = threadIdx.x, ty = threadIdx.y;
  const int tid = ty * TW + tx;
  const int b = blockIdx.z;
  const int h0 = blockIdx.y * TH, w0 = blockIdx.x * TW;

  // ---- stage x tile (+halo 5, zero-padded) ----
  for (int i = tid; i < NCELL; i += TW * TH) {
    int r = i / LR_COLS, cc = i - r * LR_COLS;
    int gh = h0 - HALO + r, gw = w0 - HALO + cc;
    bool ok = (gh >= 0) & (gh < HH) & (gw >= 0) & (gw < WW);
    const float* xp = x + (size_t)b * (CIN * HW) + gh * WW + gw;
#pragma unroll
    for (int q = 0; q < 4; ++q) {
      float4 v = make_float4(0.f, 0.f, 0.f, 0.f);
      if (ok) {
        v.x = xp[(q * 4 + 0) * HW];
        v.y = xp[(q * 4 + 1) * HW];
        v.z = xp[(q * 4 + 2) * HW];
        v.w = xp[(q * 4 + 3) * HW];
      }
      xt4[q * NCELLP + i] = v;
    }
  }
  __syncthreads();

  const int lbase = (ty + HALO) * LR_COLS + (tx + HALO);
  const float4 xc0 = xt4[0 * NCELLP + lbase];
  const float4 xc1 = xt4[1 * NCELLP + lbase];
  const float4 xc2 = xt4[2 * NCELLP + lbase];
  const float4 xc3 = xt4[3 * NCELLP + lbase];

  // ---- phase 1a: 14 calls into ONE pair-oct body (8-way ILP) ----
  float sgv[NP];
  pairs_call(sgv, std::make_index_sequence<NP / 8>{}, xt4, lbase, xc0, xc1, xc2, xc3);

  // ---- phase 1b: per-group numpy SSE2 pairwise tree (compile-time wiring) ----
  float sim32[16];
#pragma unroll
  for (int g = 0; g < 16; ++g) {
    float A0 = (sgv[CT.gmap[g*16+0]]  + sgv[CT.gmap[g*16+8]])
             + (sgv[CT.gmap[g*16+4]]  + sgv[CT.gmap[g*16+12]]);
    float A1 = (sgv[CT.gmap[g*16+1]]  + sgv[CT.gmap[g*16+9]])
             + (sgv[CT.gmap[g*16+5]]  + sgv[CT.gmap[g*16+13]]);
    float A2 = (sgv[CT.gmap[g*16+2]]  + sgv[CT.gmap[g*16+10]])
             + (sgv[CT.gmap[g*16+6]]  + sgv[CT.gmap[g*16+14]]);
    float A3 = (sgv[CT.gmap[g*16+3]]  + sgv[CT.gmap[g*16+11]])
             + (sgv[CT.gmap[g*16+7]]  + sgv[CT.gmap[g*16+15]]);
    float ssum = (A0 + A2) + (A1 + A3);
    sim32[g] = ssum / 16.0f;                 // exact (pow2)
  }

  // ---- selection: rolled bubble (bit-exact vs triangular version) ----
  float s16[16]; int od[16];
#pragma unroll
  for (int i = 0; i < 16; ++i) { s16[i] = sim32[i]; od[i] = i; }
#pragma clang loop unroll(disable)
  for (int p = 0; p < 15; ++p) {
#pragma unroll
    for (int j = 0; j < 15; ++j) {
      float a = s16[j], c = s16[j + 1];
      int oa = od[j], oc = od[j + 1];
      bool sw = a > c;                     // strict -> stable
      s16[j] = sw ? c : a; s16[j + 1] = sw ? a : c;
      od[j] = sw ? oc : oa; od[j + 1] = sw ? oa : oc;
    }
  }
  float best = s16[1] - s16[0]; int ori = od[0];
#pragma unroll
  for (int i = 1; i < 15; ++i) {
    float dd = s16[i + 1] - s16[i];
    if (dd > best) { best = dd; ori = od[i]; }   // strict -> first max
  }
  if (!(best >= 0.001f)) ori = 0;                // INIT_INDEX

  ori_s[tid] = ori;
  __syncthreads();

  // ---- phase 2: bf16 MFMA.  D[o][pix] = sum_k W[o,k] P[k,pix], K=256 ----
  const int lane  = tid & 63;
  const int wavei = tid >> 6;
  const int hq  = lane >> 4;         // quarter-group
  const int col = lane & 15;         // D column = pixel-within-group
  const int q0  = (hq & 1) * 2;      // this lane's channel-half chunks

  bf16x8 afr[2][8];
#pragma unroll
  for (int m = 0; m < 2; ++m)
#pragma unroll
    for (int s = 0; s < 8; ++s)
      afr[m][s] = *(const bf16x8*)(wsA + (((m * 8 + s) * 64 + lane) << 3));

  float bv[2][4];
#pragma unroll
  for (int m = 0; m < 2; ++m)
#pragma unroll
    for (int r = 0; r < 4; ++r) bv[m][r] = bias[m * 16 + hq * 4 + r];

  f32x4 acc[2][4];
#pragma unroll
  for (int m = 0; m < 2; ++m)
#pragma unroll
    for (int t = 0; t < 4; ++t)
      acc[m][t] = f32x4{bv[m][0], bv[m][1], bv[m][2], bv[m][3]};

#pragma unroll
  for (int t = 0; t < 4; ++t) {
    const int p  = wavei * 64 + t * 16 + col;   // pixel this lane serves
    const int py = p >> 5, px = p & 31;
    const int lb = (py + HALO) * LR_COLS + (px + HALO);
    const int orip = ori_s[p];
    const int4* cr = (const int4*)&DT.coff[orip * 16];
    int4 cA = cr[0], cB = cr[1];
    int dw[8] = {cA.x, cA.y, cA.z, cA.w, cB.x, cB.y, cB.z, cB.w};
    const float4 xca = xt4[q0 * NCELLP + lb];
    const float4 xcb = xt4[(q0 + 1) * NCELLP + lb];
#pragma unroll
    for (int s = 0; s < 8; ++s) {
      int pk = dw[s];
      int off16 = (hq >= 2) ? (int)(int16_t)((unsigned)pk >> 16)
                            : (int)(int16_t)(pk & 0xffff);
      int cell = lb + off16;
      float4 ra = xt4[q0 * NCELLP + cell];
      float4 rb = xt4[(q0 + 1) * NCELLP + cell];
      // x_prf = xc - xr via pk_sub, then HW pack-convert pairs to bf16 (RNE)
      f32x2 d0 = f32x2{xca.x, xca.y} - f32x2{ra.x, ra.y};
      f32x2 d1 = f32x2{xca.z, xca.w} - f32x2{ra.z, ra.w};
      f32x2 d2 = f32x2{xcb.x, xcb.y} - f32x2{rb.x, rb.y};
      f32x2 d3 = f32x2{xcb.z, xcb.w} - f32x2{rb.z, rb.w};
      i32x4 wv;
      asm("v_cvt_pk_bf16_f32 %0, %1, %2" : "=v"(wv.x) : "v"(d0.x), "v"(d0.y));
      asm("v_cvt_pk_bf16_f32 %0, %1, %2" : "=v"(wv.y) : "v"(d1.x), "v"(d1.y));
      asm("v_cvt_pk_bf16_f32 %0, %1, %2" : "=v"(wv.z) : "v"(d2.x), "v"(d2.y));
      asm("v_cvt_pk_bf16_f32 %0, %1, %2" : "=v"(wv.w) : "v"(d3.x), "v"(d3.y));
      bf16x8 bfr = __builtin_bit_cast(bf16x8, wv);
      acc[0][t] = __builtin_amdgcn_mfma_f32_16x16x32_bf16(afr[0][s], bfr, acc[0][t], 0, 0, 0);
      acc[1][t] = __builtin_amdgcn_mfma_f32_16x16x32_bf16(afr[1][s], bfr, acc[1][t], 0, 0, 0);
    }
  }

  // ---- store: D row = o = m*16 + hq*4 + r; D col = pixel p(t, col) ----
#pragma unroll
  for (int t = 0; t < 4; ++t) {
    const int p  = wavei * 64 + t * 16 + col;
    const int hh = h0 + (p >> 5), ww = w0 + (p & 31);
    float* op = out + (size_t)b * (COUT * HW) + hh * WW + ww;
#pragma unroll
    for (int m = 0; m < 2; ++m)
#pragma unroll
      for (int r = 0; r < 4; ++r)
        op[(m * 16 + hq * 4 + r) * HW] = acc[m][t][r];
  }
}

extern "C" void kernel_launch(void* const* d_in, const int* in_sizes, int n_in,
                              void* d_out, int out_size, void* d_ws, size_t ws_size,
                              hipStream_t stream) {
  const float* x    = (const float*)d_in[0];
  const float* w    = (const float*)d_in[1];
  const float* bias = (const float*)d_in[2];
  float* out = (float*)d_out;
  unsigned short* wsA = (unsigned short*)d_ws;   // 8192 bf16 = 16 KB scratch

  hipLaunchKernelGGL(pack_A, dim3(32), dim3(256), 0, stream, w, wsA);

  dim3 grid(WW / TW, HH / TH, NB);
  dim3 block(TW, TH, 1);
  hipLaunchKernelGGL(adapkc_main, grid, block, 0, stream, x, wsA, bias, out);
}

// Round 17
// 60.392 us; speedup vs baseline: 1.0474x; 1.0467x over previous
//
#include <hip/hip_runtime.h>
#include <cstdint>
#include <cstddef>
#include <utility>

#define HH 256
#define WW 256
#define CIN 16
#define COUT 32
#define NB 2
#define TW 32
#define TH 8
#define NPIX (TW*TH)            // 256 pixels/block
#define HALO 5
#define LR_ROWS (TH + 2*HALO)   // 18
#define LR_COLS (TW + 2*HALO)   // 42
#define NCELL (LR_ROWS*LR_COLS) // 756 cells staged
#define NCELLP 758              // padded plane stride
#define HW (HH*WW)

typedef float f32x2 __attribute__((ext_vector_type(2)));
typedef float f32x4 __attribute__((ext_vector_type(4)));
typedef int   i32x4 __attribute__((ext_vector_type(4)));
typedef short bf16x8 __attribute__((ext_vector_type(8)));
__device__ __forceinline__ f32x2 splat2(float v) { return f32x2{v, v}; }

// RNE f32->bf16 (bit trick == HW cvt for finite values) — used in pack_A only
__device__ __forceinline__ unsigned short f2bf(float f) {
  unsigned u = __float_as_uint(f);
  return (unsigned short)((u + 0x7fffu + ((u >> 16) & 1u)) >> 16);
}

// ---------------- compile-time offset tables ----------------
// pcoff order: [pairs only groups 0-7 | shared | pairs only groups 8-15]
// -> groups 0-7 reducible after first npa pairs; frees registers mid-phase.
struct alignas(16) Tables {
  int16_t coff[256];    // (g*16+n) -> cell offset dx*LR_COLS+dy (phase 2)
  int16_t pcoff[128];   // partitioned distinct-pair cell offsets
  uint8_t gmap[256];    // (g*16+n) -> index into pcoff order
  int np;               // total distinct pairs (112)
  int npa;              // boundary: pairs needed by groups 0..7 (68)
};

// numpy round-half-to-even for non-negative v (only .0/.5 cases occur)
constexpr int rhe(double v) {
  int f = (int)v;
  double fr = v - (double)f;
  if (fr > 0.5) return f + 1;
  if (fr < 0.5) return f;
  return (f & 1) ? f + 1 : f;
}

constexpr Tables make_tables() {
  Tables t{};
  int coa[256] = {};
  for (int g = 0; g < 16; ++g) {
    int hp = (g >> 2) + 2;   // rb + gh
    int wp = (g & 3) + 2;    // rb + gw
    int TD[5] = {}, LRr[3] = {};
    for (int j = 0; j < 5; ++j) TD[j] = rhe(j * wp / 2.0) - wp;
    for (int j = 0; j < 3; ++j) LRr[j] = rhe((j + 1) * hp / 2.0) - hp;
    int dxs[16] = {}, dys[16] = {};
    for (int j = 0; j < 5; ++j) { dxs[j]      = -hp;    dys[j]      = TD[j]; }
    for (int j = 0; j < 3; ++j) { dxs[5 + j]  = LRr[j]; dys[5 + j]  =  wp;   }
    for (int j = 0; j < 5; ++j) { dxs[8 + j]  =  hp;    dys[8 + j]  = TD[j]; }
    for (int j = 0; j < 3; ++j) { dxs[13 + j] = LRr[j]; dys[13 + j] = -wp;   }
    for (int n = 0; n < 16; ++n) {
      int co = dxs[n] * LR_COLS + dys[n];
      coa[g * 16 + n] = co;
      t.coff[g * 16 + n] = (int16_t)co;
    }
  }
  // dedup half A (groups 0-7) and half B (groups 8-15)
  int16_t A[128] = {}; int na = 0; int amap[128] = {};
  int16_t B[128] = {}; int nb = 0; int bmap[128] = {};
  bool ashr[128] = {};
  int bshA[128] = {};
  for (int g = 0; g < 8; ++g)
    for (int n = 0; n < 16; ++n) {
      int co = coa[g * 16 + n], j = -1;
      for (int k = 0; k < na; ++k) if ((int)A[k] == co) { j = k; break; }
      if (j < 0) { j = na++; A[j] = (int16_t)co; }
      amap[g * 16 + n] = j;
    }
  for (int g = 8; g < 16; ++g)
    for (int n = 0; n < 16; ++n) {
      int co = coa[g * 16 + n], k = -1;
      for (int m = 0; m < nb; ++m) if ((int)B[m] == co) { k = m; break; }
      if (k < 0) { k = nb++; B[k] = (int16_t)co; }
      bmap[(g - 8) * 16 + n] = k;
    }
  for (int k = 0; k < nb; ++k) {
    bshA[k] = -1;
    for (int j = 0; j < na; ++j)
      if (A[j] == B[k]) { bshA[k] = j; ashr[j] = true; break; }
  }
  int posA[128] = {}, posB[128] = {};
  int p = 0;
  for (int j = 0; j < na; ++j) if (!ashr[j]) posA[j] = p++;
  for (int j = 0; j < na; ++j) if (ashr[j])  posA[j] = p++;
  t.npa = p;                                  // == na
  for (int k = 0; k < nb; ++k) posB[k] = (bshA[k] >= 0) ? posA[bshA[k]] : p++;
  t.np = p;
  for (int j = 0; j < na; ++j) t.pcoff[posA[j]] = A[j];
  for (int k = 0; k < nb; ++k) t.pcoff[posB[k]] = B[k];
  for (int g = 0; g < 8; ++g)
    for (int n = 0; n < 16; ++n) t.gmap[g * 16 + n] = (uint8_t)posA[amap[g * 16 + n]];
  for (int g = 8; g < 16; ++g)
    for (int n = 0; n < 16; ++n) t.gmap[g * 16 + n] = (uint8_t)posB[bmap[(g - 8) * 16 + n]];
  return t;
}

constexpr Tables CT = make_tables();
constexpr int NP  = CT.np;
constexpr int NPA = CT.npa;
static_assert(NP <= 128 && NP % 4 == 0, "pair table");
static_assert(NPA % 4 == 0, "pass-1 boundary not quad-aligned");
__device__ const Tables DT = make_tables();   // for runtime-indexed phase-2 reads

// ------- exact transcription of numpy's SIMD f32 exp, 2-wide packed -------
__device__ __forceinline__ f32x2 numpy_expf2(f32x2 v) {
#pragma clang fp contract(off)
  const f32x2 MAGIC = splat2(12582912.0f);         // 1.5 * 2^23
  f32x2 q = __builtin_elementwise_fma(v, splat2(1.442695040888963407359e+00f), MAGIC);
  q = q - MAGIC;                                   // rint(v*log2e), single rounding
  f32x2 r = __builtin_elementwise_fma(q, splat2(-6.93145752e-1f), v);
  r = __builtin_elementwise_fma(q, splat2(-1.42860677e-6f), r);
  f32x2 num = __builtin_elementwise_fma(splat2(5.082762527590693718096e-04f), r,
                                        splat2(6.757896990527504603057e-03f));
  num = __builtin_elementwise_fma(num, r, splat2(5.114512081637298353406e-02f));
  num = __builtin_elementwise_fma(num, r, splat2(2.473615434895520810817e-01f));
  num = __builtin_elementwise_fma(num, r, splat2(7.257664613233124478488e-01f));
  num = __builtin_elementwise_fma(num, r, splat2(9.999999999980870924916e-01f));
  f32x2 den = __builtin_elementwise_fma(splat2(2.159509375685829852307e-02f), r,
                                        splat2(-2.742335390411667452936e-01f));
  den = __builtin_elementwise_fma(den, r, splat2(1.0f));
  f32x2 res;
  res.x = ldexpf(num.x / den.x, (int)q.x);         // IEEE div + exact pow2 scale
  res.y = ldexpf(num.y / den.y, (int)q.y);
  return res;
}

// ---- shared pair-quad body: all 16 loads issued FIRST (pinned), then compute ----
__device__ __attribute__((noinline))
float4 pair4(const float4* __restrict__ xt4, int c0, int c1, int c2, int c3,
             float4 xc0, float4 xc1, float4 xc2, float4 xc3)
{
#pragma clang fp contract(off)
  float4 Ra0 = xt4[0 * NCELLP + c0], Ra1 = xt4[1 * NCELLP + c0];
  float4 Ra2 = xt4[2 * NCELLP + c0], Ra3 = xt4[3 * NCELLP + c0];
  float4 Rb0 = xt4[0 * NCELLP + c1], Rb1 = xt4[1 * NCELLP + c1];
  float4 Rb2 = xt4[2 * NCELLP + c1], Rb3 = xt4[3 * NCELLP + c1];
  float4 Rc0 = xt4[0 * NCELLP + c2], Rc1 = xt4[1 * NCELLP + c2];
  float4 Rc2 = xt4[2 * NCELLP + c2], Rc3 = xt4[3 * NCELLP + c2];
  float4 Rd0 = xt4[0 * NCELLP + c3], Rd1 = xt4[1 * NCELLP + c3];
  float4 Rd2 = xt4[2 * NCELLP + c3], Rd3 = xt4[3 * NCELLP + c3];
  __builtin_amdgcn_sched_barrier(0);   // keep all 16 loads in flight above compute

  const f32x2 xcl[8] = { {xc0.x,xc0.y},{xc0.z,xc0.w},{xc1.x,xc1.y},{xc1.z,xc1.w},
                         {xc2.x,xc2.y},{xc2.z,xc2.w},{xc3.x,xc3.y},{xc3.z,xc3.w} };
  float mloc[4];
#pragma unroll
  for (int j = 0; j < 4; ++j) {
    float4 R0 = (j == 0) ? Ra0 : (j == 1) ? Rb0 : (j == 2) ? Rc0 : Rd0;
    float4 R1 = (j == 0) ? Ra1 : (j == 1) ? Rb1 : (j == 2) ? Rc1 : Rd1;
    float4 R2 = (j == 0) ? Ra2 : (j == 1) ? Rb2 : (j == 2) ? Rc2 : Rd2;
    float4 R3 = (j == 0) ? Ra3 : (j == 1) ? Rb3 : (j == 2) ? Rc3 : Rd3;
    // products rounded individually (v_pk_mul pairs 2 IEEE muls/slot)
    f32x2 pr[8];
    pr[0] = f32x2{R0.x, R0.y} * xcl[0];  pr[1] = f32x2{R0.z, R0.w} * xcl[1];
    pr[2] = f32x2{R1.x, R1.y} * xcl[2];  pr[3] = f32x2{R1.z, R1.w} * xcl[3];
    pr[4] = f32x2{R2.x, R2.y} * xcl[4];  pr[5] = f32x2{R2.z, R2.w} * xcl[5];
    pr[6] = f32x2{R3.x, R3.y} * xcl[6];  pr[7] = f32x2{R3.z, R3.w} * xcl[7];
    // sequential channel sum c=0..15 (numpy outer-axis reduce), unfused
    float s = pr[0].x;
    s += pr[0].y; s += pr[1].x; s += pr[1].y;
    s += pr[2].x; s += pr[2].y; s += pr[3].x; s += pr[3].y;
    s += pr[4].x; s += pr[4].y; s += pr[5].x; s += pr[5].y;
    s += pr[6].x; s += pr[6].y; s += pr[7].x; s += pr[7].y;
    mloc[j] = s / 16.0f;                     // exact (pow2)
  }
  f32x2 e0 = numpy_expf2(-f32x2{mloc[0], mloc[1]});
  f32x2 e1 = numpy_expf2(-f32x2{mloc[2], mloc[3]});
  f32x2 d0 = splat2(1.0f) + e0;
  f32x2 d1 = splat2(1.0f) + e1;
  float4 outv;
  outv.x = 1.0f / d0.x; outv.y = 1.0f / d0.y;      // IEEE f32 div
  outv.z = 1.0f / d1.x; outv.w = 1.0f / d1.y;
  return outv;
}

template<int OFS, size_t... BB>
__device__ __forceinline__ void pairs_call(float* sgv, std::index_sequence<BB...>,
    const float4* xt4, int lbase, float4 xc0, float4 xc1, float4 xc2, float4 xc3)
{
  ((void)([&] {
    float4 r = pair4(xt4,
                     lbase + (int)CT.pcoff[OFS + BB*4 + 0], lbase + (int)CT.pcoff[OFS + BB*4 + 1],
                     lbase + (int)CT.pcoff[OFS + BB*4 + 2], lbase + (int)CT.pcoff[OFS + BB*4 + 3],
                     xc0, xc1, xc2, xc3);
    sgv[OFS + BB*4 + 0] = r.x; sgv[OFS + BB*4 + 1] = r.y;   // static idx -> registers
    sgv[OFS + BB*4 + 2] = r.z; sgv[OFS + BB*4 + 3] = r.w;
  }()), ...);
}

// numpy SSE2 pairwise tree for groups [G0, G0+8) — retires sgv registers early
template<int G0>
__device__ __forceinline__ void reduce8(float* sim32, const float* sgv)
{
#pragma clang fp contract(off)
#pragma unroll
  for (int gg = 0; gg < 8; ++gg) {
    const int g = G0 + gg;
    float A0 = (sgv[CT.gmap[g*16+0]]  + sgv[CT.gmap[g*16+8]])
             + (sgv[CT.gmap[g*16+4]]  + sgv[CT.gmap[g*16+12]]);
    float A1 = (sgv[CT.gmap[g*16+1]]  + sgv[CT.gmap[g*16+9]])
             + (sgv[CT.gmap[g*16+5]]  + sgv[CT.gmap[g*16+13]]);
    float A2 = (sgv[CT.gmap[g*16+2]]  + sgv[CT.gmap[g*16+10]])
             + (sgv[CT.gmap[g*16+6]]  + sgv[CT.gmap[g*16+14]]);
    float A3 = (sgv[CT.gmap[g*16+3]]  + sgv[CT.gmap[g*16+11]])
             + (sgv[CT.gmap[g*16+7]]  + sgv[CT.gmap[g*16+15]]);
    float ssum = (A0 + A2) + (A1 + A3);
    sim32[g] = ssum / 16.0f;                 // exact (pow2)
  }
}

// -------- A-operand pack: w[o][c][n] -> per-lane MFMA fragment order --------
__global__ void pack_A(const float* __restrict__ w, unsigned short* __restrict__ wsA) {
  int i = blockIdx.x * 256 + threadIdx.x;
  if (i < 2 * 8 * 64 * 8) {
    int m = i >> 12, s = (i >> 9) & 7, l = (i >> 3) & 63, j = i & 7;
    int h = l >> 4, col = l & 15;
    int o = m * 16 + col;
    int n = 2 * s + (h >> 1);
    int c = (h & 1) * 8 + j;
    wsA[i] = f2bf(w[(o * CIN + c) * 16 + n]);
  }
}

// ---------------- fused main kernel ----------------
__global__ __launch_bounds__(TW * TH)
__attribute__((amdgpu_waves_per_eu(2, 2)))
void adapkc_main(
    const float* __restrict__ x, const unsigned short* __restrict__ wsA,
    const float* __restrict__ bias, float* __restrict__ out)
{
#pragma clang fp contract(off)   // numpy never fuses mul+add; keep every rounding
  __shared__ float4 xt4[4 * NCELLP];         // 48,512 B
  __shared__ int    ori_s[NPIX];             //  1,024 B

  const int tx = threadIdx.x, ty = threadIdx.y;
  const int tid = ty * TW + tx;
  const int b = blockIdx.z;
  const int h0 = blockIdx.y * TH, w0 = blockIdx.x * TW;

  // ---- stage x tile (+halo 5, zero-padded) ----
  for (int i = tid; i < NCELL; i += TW * TH) {
    int r = i / LR_COLS, cc = i - r * LR_COLS;
    int gh = h0 - HALO + r, gw = w0 - HALO + cc;
    bool ok = (gh >= 0) & (gh < HH) & (gw >= 0) & (gw < WW);
    const float* xp = x + (size_t)b * (CIN * HW) + gh * WW + gw;
#pragma unroll
    for (int q = 0; q < 4; ++q) {
      float4 v = make_float4(0.f, 0.f, 0.f, 0.f);
      if (ok) {
        v.x = xp[(q * 4 + 0) * HW];
        v.y = xp[(q * 4 + 1) * HW];
        v.z = xp[(q * 4 + 2) * HW];
        v.w = xp[(q * 4 + 3) * HW];
      }
      xt4[q * NCELLP + i] = v;
    }
  }
  __syncthreads();

  const int lbase = (ty + HALO) * LR_COLS + (tx + HALO);
  const float4 xc0 = xt4[0 * NCELLP + lbase];
  const float4 xc1 = xt4[1 * NCELLP + lbase];
  const float4 xc2 = xt4[2 * NCELLP + lbase];
  const float4 xc3 = xt4[3 * NCELLP + lbase];

  // ---- phase 1: two passes, reducing groups 0-7 mid-way to retire registers ----
  float sgv[NP];
  float sim32[16];
  pairs_call<0>(sgv, std::make_index_sequence<NPA / 4>{},
                xt4, lbase, xc0, xc1, xc2, xc3);
  reduce8<0>(sim32, sgv);                    // frees sgv[0..NPA) minus shared
  pairs_call<NPA>(sgv, std::make_index_sequence<(NP - NPA) / 4>{},
                  xt4, lbase, xc0, xc1, xc2, xc3);
  reduce8<8>(sim32, sgv);

  // ---- selection: rolled bubble (bit-exact vs triangular version) ----
  float s16[16]; int od[16];
#pragma unroll
  for (int i = 0; i < 16; ++i) { s16[i] = sim32[i]; od[i] = i; }
#pragma clang loop unroll(disable)
  for (int p = 0; p < 15; ++p) {
#pragma unroll
    for (int j = 0; j < 15; ++j) {
      float a = s16[j], c = s16[j + 1];
      int oa = od[j], oc = od[j + 1];
      bool sw = a > c;                     // strict -> stable
      s16[j] = sw ? c : a; s16[j + 1] = sw ? a : c;
      od[j] = sw ? oc : oa; od[j + 1] = sw ? oa : oc;
    }
  }
  float best = s16[1] - s16[0]; int ori = od[0];
#pragma unroll
  for (int i = 1; i < 15; ++i) {
    float dd = s16[i + 1] - s16[i];
    if (dd > best) { best = dd; ori = od[i]; }   // strict -> first max
  }
  if (!(best >= 0.001f)) ori = 0;                // INIT_INDEX

  ori_s[tid] = ori;
  __syncthreads();

  // ---- phase 2: bf16 MFMA.  D[o][pix] = sum_k W[o,k] P[k,pix], K=256 ----
  const int lane  = tid & 63;
  const int wavei = tid >> 6;
  const int hq  = lane >> 4;         // quarter-group
  const int col = lane & 15;         // D column = pixel-within-group
  const int q0  = (hq & 1) * 2;      // this lane's channel-half chunks

  bf16x8 afr[2][8];
#pragma unroll
  for (int m = 0; m < 2; ++m)
#pragma unroll
    for (int s = 0; s < 8; ++s)
      afr[m][s] = *(const bf16x8*)(wsA + (((m * 8 + s) * 64 + lane) << 3));

  float bv[2][4];
#pragma unroll
  for (int m = 0; m < 2; ++m)
#pragma unroll
    for (int r = 0; r < 4; ++r) bv[m][r] = bias[m * 16 + hq * 4 + r];

  f32x4 acc[2][4];
#pragma unroll
  for (int m = 0; m < 2; ++m)
#pragma unroll
    for (int t = 0; t < 4; ++t)
      acc[m][t] = f32x4{bv[m][0], bv[m][1], bv[m][2], bv[m][3]};

#pragma unroll
  for (int t = 0; t < 4; ++t) {
    const int p  = wavei * 64 + t * 16 + col;   // pixel this lane serves
    const int py = p >> 5, px = p & 31;
    const int lb = (py + HALO) * LR_COLS + (px + HALO);
    const int orip = ori_s[p];
    const int4* cr = (const int4*)&DT.coff[orip * 16];
    int4 cA = cr[0], cB = cr[1];
    int dw[8] = {cA.x, cA.y, cA.z, cA.w, cB.x, cB.y, cB.z, cB.w};
    const float4 xca = xt4[q0 * NCELLP + lb];
    const float4 xcb = xt4[(q0 + 1) * NCELLP + lb];
#pragma unroll
    for (int s = 0; s < 8; ++s) {
      int pk = dw[s];
      int off16 = (hq >= 2) ? (int)(int16_t)((unsigned)pk >> 16)
                            : (int)(int16_t)(pk & 0xffff);
      int cell = lb + off16;
      float4 ra = xt4[q0 * NCELLP + cell];
      float4 rb = xt4[(q0 + 1) * NCELLP + cell];
      f32x2 d0 = f32x2{xca.x, xca.y} - f32x2{ra.x, ra.y};
      f32x2 d1 = f32x2{xca.z, xca.w} - f32x2{ra.z, ra.w};
      f32x2 d2 = f32x2{xcb.x, xcb.y} - f32x2{rb.x, rb.y};
      f32x2 d3 = f32x2{xcb.z, xcb.w} - f32x2{rb.z, rb.w};
      i32x4 wv;
      asm("v_cvt_pk_bf16_f32 %0, %1, %2" : "=v"(wv.x) : "v"(d0.x), "v"(d0.y));
      asm("v_cvt_pk_bf16_f32 %0, %1, %2" : "=v"(wv.y) : "v"(d1.x), "v"(d1.y));
      asm("v_cvt_pk_bf16_f32 %0, %1, %2" : "=v"(wv.z) : "v"(d2.x), "v"(d2.y));
      asm("v_cvt_pk_bf16_f32 %0, %1, %2" : "=v"(wv.w) : "v"(d3.x), "v"(d3.y));
      bf16x8 bfr = __builtin_bit_cast(bf16x8, wv);
      acc[0][t] = __builtin_amdgcn_mfma_f32_16x16x32_bf16(afr[0][s], bfr, acc[0][t], 0, 0, 0);
      acc[1][t] = __builtin_amdgcn_mfma_f32_16x16x32_bf16(afr[1][s], bfr, acc[1][t], 0, 0, 0);
    }
  }

  // ---- store: D row = o = m*16 + hq*4 + r; D col = pixel p(t, col) ----
#pragma unroll
  for (int t = 0; t < 4; ++t) {
    const int p  = wavei * 64 + t * 16 + col;
    const int hh = h0 + (p >> 5), ww = w0 + (p & 31);
    float* op = out + (size_t)b * (COUT * HW) + hh * WW + ww;
#pragma unroll
    for (int m = 0; m < 2; ++m)
#pragma unroll
      for (int r = 0; r < 4; ++r)
        op[(m * 16 + hq * 4 + r) * HW] = acc[m][t][r];
  }
}

extern "C" void kernel_launch(void* const* d_in, const int* in_sizes, int n_in,
                              void* d_out, int out_size, void* d_ws, size_t ws_size,
                              hipStream_t stream) {
  const float* x    = (const float*)d_in[0];
  const float* w    = (const float*)d_in[1];
  const float* bias = (const float*)d_in[2];
  float* out = (float*)d_out;
  unsigned short* wsA = (unsigned short*)d_ws;   // 8192 bf16 = 16 KB scratch

  hipLaunchKernelGGL(pack_A, dim3(32), dim3(256), 0, stream, w, wsA);

  dim3 grid(WW / TW, HH / TH, NB);
  dim3 block(TW, TH, 1);
  hipLaunchKernelGGL(adapkc_main, grid, block, 0, stream, x, wsA, bias, out);
}